// Round 3
// baseline (2012.411 us; speedup 1.0000x reference)
//
#include <hip/hip_runtime.h>

#define B_ 16
#define T_ 24
#define N_ 207
#define D_ 512
#define L_ 2
#define M_ (B_*N_)        // 3312 rows
#define G3 (3*D_)         // 1536
#define APAD 56           // LDS k-stride in shorts (112B = 28 banks, 16B aligned)

typedef __attribute__((ext_vector_type(8))) unsigned short ushort8;
typedef __attribute__((ext_vector_type(8))) _Float16 half8;
typedef __attribute__((ext_vector_type(4))) float f32x4;

static __device__ __forceinline__ unsigned short f2h(float f) {
    union { _Float16 h; unsigned short u; } c;
    c.h = (_Float16)f;
    return c.u;
}

// ---------------------------------------------------------------------------
// Weight prep: wt[l][g][n][k] = fp16(W(l, k, (g%3)*512 + n)), g<3 Wi, g>=3 Wh
// ---------------------------------------------------------------------------
__global__ __launch_bounds__(256)
void prep_w(const float* __restrict__ Wi, const float* __restrict__ Wh,
            unsigned short* __restrict__ wt)
{
    __shared__ float tile[32][33];
    const int z = blockIdx.z;           // l*6 + g
    const int l = z / 6, g = z % 6;
    const float* W = (g < 3 ? Wi : Wh) + (long)l * D_ * G3;
    const int gc = (g % 3) * D_;
    const int k0 = blockIdx.x * 32, n0 = blockIdx.y * 32;
    const int tx = threadIdx.x & 31, ty = threadIdx.x >> 5;
#pragma unroll
    for (int j = 0; j < 4; ++j)
        tile[ty + 8*j][tx] = W[(long)(k0 + ty + 8*j) * G3 + gc + n0 + tx];
    __syncthreads();
#pragma unroll
    for (int j = 0; j < 4; ++j)
        wt[((long)z * D_ + n0 + ty + 8*j) * D_ + k0 + tx] = f2h(tile[tx][ty + 8*j]);
}

// ---------------------------------------------------------------------------
// h[l][b*N+n][d] = h0[b][l][n][d]
// ---------------------------------------------------------------------------
__global__ __launch_bounds__(256)
void init_h(const float* __restrict__ h0, float* __restrict__ h)
{
    long i = ((long)blockIdx.x * 256 + threadIdx.x) * 4;
    if (i >= (long)L_ * M_ * D_) return;
    int l = (int)(i / ((long)M_ * D_));
    long rem = i - (long)l * M_ * D_;
    int row = (int)(rem / D_);
    int d = (int)(rem - (long)row * D_);
    int b = row / N_, n = row - b * N_;
    *(float4*)(h + (long)l * M_ * D_ + rem) =
        *(const float4*)(h0 + (((long)(b * L_ + l) * N_ + n) * D_ + d));
}

__global__ __launch_bounds__(256)
void copy_hidden(const float* __restrict__ h, float* __restrict__ outp)
{
    long i = ((long)blockIdx.x * 256 + threadIdx.x) * 4;
    if (i >= (long)L_ * M_ * D_) return;
    int l = (int)(i / ((long)M_ * D_));
    long rem = i - (long)l * M_ * D_;
    int row = (int)(rem / D_);
    int d = (int)(rem - (long)row * D_);
    int b = row / N_, n = row - b * N_;
    *(float4*)(outp + (((long)(b * L_ + l) * N_ + n) * D_ + d)) =
        *(const float4*)(h + (long)l * M_ * D_ + rem);
}

// ---------------------------------------------------------------------------
// Fused GRU cell GEMM: per block, 64 rows x 64 out-cols, six gate tiles,
// K = 512. A operands (x slice or h) are fp32 in global, converted to fp16
// while staging to LDS. Weights already fp16-transposed in wt.
// Epilogue applies biases + gating, writes pre-LN out.
// ---------------------------------------------------------------------------
__global__ __launch_bounds__(256, 2)
void cell_kernel(const float* __restrict__ Ax, const float* __restrict__ Ah,
                 const unsigned short* __restrict__ wtl,
                 const float* __restrict__ bi_l, const float* __restrict__ bh_l,
                 float* __restrict__ pre, int t, int ax_is_x)
{
    __shared__ __align__(16) unsigned short As[64][APAD];
    __shared__ __align__(16) unsigned short Hs[64][APAD];
    __shared__ __align__(16) unsigned short Bs[6][64][APAD];

    const int tid = threadIdx.x;
    const int rt = blockIdx.x, cg = blockIdx.y;
    const int row0 = rt * 64;

    // staging map: thread -> (srow 0..63, skk in {0,8,16,24})
    const int srow = tid >> 2;
    const int skk  = (tid & 3) << 3;

    int gr = row0 + srow; if (gr >= M_) gr = M_ - 1;
    const float* axp;
    if (ax_is_x) {
        int b = gr / N_;
        axp = Ax + ((long)(b * (T_ - 1) + t) * N_ + gr) * D_ + skk;
    } else {
        axp = Ax + (long)gr * D_ + skk;
    }
    const float* ahp = Ah + (long)gr * D_ + skk;

    f32x4 acc[6][4];
#pragma unroll
    for (int g = 0; g < 6; ++g)
#pragma unroll
        for (int i = 0; i < 4; ++i) acc[g][i] = (f32x4){0.f, 0.f, 0.f, 0.f};

    const int lane = tid & 63;
    const int wv = tid >> 6;
    const int lr = lane & 15;
    const int kq = (lane >> 4) << 3;      // k offset within 32: 0,8,16,24
    const int wcol = wv * 16 + lr;        // col 0..63 within tile

    for (int it = 0; it < 16; ++it) {
        const int k0 = it * 32;
        float4 x0 = *(const float4*)(axp + k0);
        float4 x1 = *(const float4*)(axp + k0 + 4);
        float4 h0v = *(const float4*)(ahp + k0);
        float4 h1v = *(const float4*)(ahp + k0 + 4);
        ushort8 bv[6];
#pragma unroll
        for (int g = 0; g < 6; ++g)
            bv[g] = *(const ushort8*)(wtl + (long)(g * 512 + cg * 64 + srow) * 512 + k0 + skk);

        __syncthreads();   // previous iteration's reads done

        ushort8 xa, ha;
        xa[0]=f2h(x0.x); xa[1]=f2h(x0.y); xa[2]=f2h(x0.z); xa[3]=f2h(x0.w);
        xa[4]=f2h(x1.x); xa[5]=f2h(x1.y); xa[6]=f2h(x1.z); xa[7]=f2h(x1.w);
        ha[0]=f2h(h0v.x); ha[1]=f2h(h0v.y); ha[2]=f2h(h0v.z); ha[3]=f2h(h0v.w);
        ha[4]=f2h(h1v.x); ha[5]=f2h(h1v.y); ha[6]=f2h(h1v.z); ha[7]=f2h(h1v.w);
        *(ushort8*)&As[srow][skk] = xa;
        *(ushort8*)&Hs[srow][skk] = ha;
#pragma unroll
        for (int g = 0; g < 6; ++g)
            *(ushort8*)&Bs[g][srow][skk] = bv[g];

        __syncthreads();

        half8 af[4], hf[4], bfr[6];
#pragma unroll
        for (int i = 0; i < 4; ++i) {
            af[i] = *(const half8*)&As[16*i + lr][kq];
            hf[i] = *(const half8*)&Hs[16*i + lr][kq];
        }
#pragma unroll
        for (int g = 0; g < 6; ++g)
            bfr[g] = *(const half8*)&Bs[g][wcol][kq];
#pragma unroll
        for (int g = 0; g < 6; ++g)
#pragma unroll
            for (int i = 0; i < 4; ++i)
                acc[g][i] = __builtin_amdgcn_mfma_f32_16x16x32_f16(
                    (g < 3) ? af[i] : hf[i], bfr[g], acc[g][i], 0, 0, 0);
    }

    // epilogue: biases + gating
    const int colg = cg * 64 + wcol;   // 0..511
    const float bir = bi_l[colg],       biz = bi_l[512 + colg], bin_ = bi_l[1024 + colg];
    const float bhr = bh_l[colg],       bhz = bh_l[512 + colg], bhn  = bh_l[1024 + colg];
#pragma unroll
    for (int i = 0; i < 4; ++i) {
        int rbase = row0 + 16*i + ((lane >> 4) << 2);
#pragma unroll
        for (int r = 0; r < 4; ++r) {
            int grow = rbase + r;
            if (grow < M_) {
                float ir = acc[0][i][r] + bir;
                float iz = acc[1][i][r] + biz;
                float inn = acc[2][i][r] + bin_;
                float hr = acc[3][i][r] + bhr;
                float hz = acc[4][i][r] + bhz;
                float hn = acc[5][i][r] + bhn;
                float rg = 1.f / (1.f + __expf(-(ir + hr)));
                float zg = 1.f / (1.f + __expf(-(iz + hz)));
                float pn = inn + rg * hn;
                float nv = 1.f - 2.f / (__expf(2.f * pn) + 1.f);   // tanh
                float hval = Ah[(long)grow * D_ + colg];
                pre[(long)grow * D_ + colg] = nv + zg * (hval - nv);
            }
        }
    }
}

// ---------------------------------------------------------------------------
// LayerNorm: one wave per row (512 = 64 lanes x 8). Writes h[l]; for l==1
// also writes the output slice out[b, t, n, :].
// ---------------------------------------------------------------------------
__global__ __launch_bounds__(256)
void ln_kernel(const float* __restrict__ pre, const float* __restrict__ gam,
               const float* __restrict__ bet, float* __restrict__ hbuf,
               float* __restrict__ outp, int t)
{
    const int wv = threadIdx.x >> 6, lane = threadIdx.x & 63;
    const int row = blockIdx.x * 4 + wv;
    if (row >= M_) return;
    const float* p = pre + (long)row * D_ + lane * 8;
    float4 v0 = *(const float4*)p;
    float4 v1 = *(const float4*)(p + 4);
    float s = (v0.x + v0.y) + (v0.z + v0.w) + (v1.x + v1.y) + (v1.z + v1.w);
    float q = v0.x*v0.x + v0.y*v0.y + v0.z*v0.z + v0.w*v0.w
            + v1.x*v1.x + v1.y*v1.y + v1.z*v1.z + v1.w*v1.w;
#pragma unroll
    for (int o = 32; o >= 1; o >>= 1) {
        s += __shfl_xor(s, o, 64);
        q += __shfl_xor(q, o, 64);
    }
    float mu = s * (1.f / D_);
    float var = q * (1.f / D_) - mu * mu;
    if (var < 0.f) var = 0.f;
    float rstd = rsqrtf(var + 1e-5f);
    const int d = lane * 8;
    float4 g0 = *(const float4*)(gam + d), g1 = *(const float4*)(gam + d + 4);
    float4 b0 = *(const float4*)(bet + d), b1 = *(const float4*)(bet + d + 4);
    float4 y0, y1;
    y0.x = (v0.x - mu) * rstd * g0.x + b0.x;
    y0.y = (v0.y - mu) * rstd * g0.y + b0.y;
    y0.z = (v0.z - mu) * rstd * g0.z + b0.z;
    y0.w = (v0.w - mu) * rstd * g0.w + b0.w;
    y1.x = (v1.x - mu) * rstd * g1.x + b1.x;
    y1.y = (v1.y - mu) * rstd * g1.y + b1.y;
    y1.z = (v1.z - mu) * rstd * g1.z + b1.z;
    y1.w = (v1.w - mu) * rstd * g1.w + b1.w;
    *(float4*)(hbuf + (long)row * D_ + d) = y0;
    *(float4*)(hbuf + (long)row * D_ + d + 4) = y1;
    if (outp) {
        int b = row / N_, n = row - b * N_;
        long off = ((long)(b * T_ + t) * N_ + n) * D_ + d;
        *(float4*)(outp + off) = y0;
        *(float4*)(outp + off + 4) = y1;
    }
}

// ---------------------------------------------------------------------------
extern "C" void kernel_launch(void* const* d_in, const int* in_sizes, int n_in,
                              void* d_out, int out_size, void* d_ws, size_t ws_size,
                              hipStream_t stream)
{
    const float* x     = (const float*)d_in[0];
    const float* h0    = (const float*)d_in[1];
    const float* Wi    = (const float*)d_in[2];
    const float* bi    = (const float*)d_in[3];
    const float* Wh    = (const float*)d_in[4];
    const float* bh    = (const float*)d_in[5];
    const float* gamma = (const float*)d_in[6];
    const float* beta  = (const float*)d_in[7];
    float* out = (float*)d_out;

    char* ws = (char*)d_ws;
    unsigned short* wt = (unsigned short*)ws;                        // 6,291,456 B
    float* h   = (float*)(ws + 6291456);                             // 13,565,952 B
    float* pre = (float*)(ws + 6291456 + 13565952);                  // 6,782,976 B

    prep_w<<<dim3(16, 16, 12), 256, 0, stream>>>(Wi, Wh, wt);
    init_h<<<3312, 256, 0, stream>>>(h0, h);

    for (int t = 0; t < T_; ++t) {
        // layer 0: Ax = x[:, t] (strided), Ah = h[0]
        cell_kernel<<<dim3(52, 8), 256, 0, stream>>>(
            x, h, wt, bi, bh, pre, t, 1);
        ln_kernel<<<828, 256, 0, stream>>>(pre, gamma, beta, h, nullptr, t);
        // layer 1: Ax = h[0] (just updated), Ah = h[1]
        cell_kernel<<<dim3(52, 8), 256, 0, stream>>>(
            h, h + (long)M_ * D_, wt + 6 * 512 * 512, bi + G3, bh + G3, pre, t, 0);
        ln_kernel<<<828, 256, 0, stream>>>(pre, gamma + D_, beta + D_,
                                           h + (long)M_ * D_, out, t);
    }

    copy_hidden<<<3312, 256, 0, stream>>>(h, out + (long)B_ * T_ * N_ * D_);
}